// Round 7
// baseline (9617.029 us; speedup 1.0000x reference)
//
#include <hip/hip_runtime.h>
#include <hip/hip_bf16.h>

// SliceLSTM persistent kernel for gfx950, round 11: tag-in-data exchange.
// 128 blocks x 256 thr (4 batch quarters x 32 j-tiles, wave = gate).
// ALL flag barriers removed. Cross-block exchange words are u32 =
// (bf16 value << 16) | step_tag; readers poll the DATA until every lane's
// tags match the expected step (one L3 RT in the common case), writers
// never drain. Safety: ping-pong act planes + the mutual 32-wide data
// dependence bound any block's lead to one step, so a live tag is never
// overwritten while a reader still needs it; stale/partial states are
// caught by the tag check and retried (watchdog-bounded).
// Weight hi-planes in LDS, lo-planes in VGPRs (unchanged, verified).
// out-store + x(t+1) prefetch issued after the act poll so their in-order
// vmcnt acks hide under the connector GEMM instead of gating a poll.

typedef unsigned short u16;
typedef unsigned long long u64;
typedef __attribute__((ext_vector_type(8))) short short8;
typedef __attribute__((ext_vector_type(4))) float floatx4;

#define NT 256
#define NBLK 128
#define TSTEPS 512

// ---- workspace layout (bytes) ----
#define WS_H 0                       // 64 b x 512 j u32 (tagged h)
#define WS_ACT 131072                // 2 planes x [4g][64b][512k] u32 (tagged)
#define ACT_PLANE_U32 131072         // u32 elements per plane
#define WS_ZERO_BYTES (131072 + 2 * 524288)  // 1179648 B, zeroed every call

__device__ __forceinline__ float b2f(u16 u) {
  unsigned v = ((unsigned)u) << 16;
  float f;
  __builtin_memcpy(&f, &v, 4);
  return f;
}
__device__ __forceinline__ u16 f2b(float f) {
  __hip_bfloat16 h = __float2bfloat16(f);  // RNE
  u16 u;
  __builtin_memcpy(&u, &h, 2);
  return u;
}
__device__ __forceinline__ float sigf(float x) { return 1.0f / (1.0f + __expf(-x)); }
__device__ __forceinline__ float tanhf_fast(float x) { return 2.0f * sigf(2.0f * x) - 1.0f; }
__device__ __forceinline__ short8 ld8(const u16* p) { return *(const short8*)p; }

__device__ __forceinline__ u64 ald64(const u64* p) {
  return __hip_atomic_load(p, __ATOMIC_RELAXED, __HIP_MEMORY_SCOPE_AGENT);
}
__device__ __forceinline__ void ast32(unsigned* p, unsigned v) {
  __hip_atomic_store(p, v, __ATOMIC_RELAXED, __HIP_MEMORY_SCOPE_AGENT);
}

__device__ __forceinline__ void split8v(float4 a, float4 b, short8& hi, short8& lo) {
  float v[8] = {a.x, a.y, a.z, a.w, b.x, b.y, b.z, b.w};
#pragma unroll
  for (int i = 0; i < 8; ++i) {
    u16 h = f2b(v[i]);
    hi[i] = (short)h;
    lo[i] = (short)f2b(v[i] - b2f(h));
  }
}

#define TAG_MASK 0x0000ffff0000ffffULL

// extract two bf16 hi-halves of a tagged u64 into short8 slots
#define EXTRACT4(dst, d0, d1, d2, d3)              \
  do {                                             \
    dst[0] = (short)((d0) >> 16);                  \
    dst[1] = (short)((d0) >> 48);                  \
    dst[2] = (short)((d1) >> 16);                  \
    dst[3] = (short)((d1) >> 48);                  \
    dst[4] = (short)((d2) >> 16);                  \
    dst[5] = (short)((d2) >> 48);                  \
    dst[6] = (short)((d3) >> 16);                  \
    dst[7] = (short)((d3) >> 48);                  \
  } while (0)

__global__ void __launch_bounds__(NT) init_ws_kernel(unsigned* w, int n) {
  int i = blockIdx.x * blockDim.x + threadIdx.x;
  const int st = gridDim.x * blockDim.x;
  for (; i < n; i += st) w[i] = 0u;
}

__global__ void __launch_bounds__(NT, 1) slicelstm_kernel(
    const float* __restrict__ x, const float* __restrict__ Ws,
    const float* __restrict__ Us, const float* __restrict__ biases,
    const float* __restrict__ Wc, const float* __restrict__ bcg,
    float* __restrict__ out, unsigned* __restrict__ actbuf,
    unsigned* __restrict__ hbuf) {
  __shared__ __align__(16) u16 W1H[64 * 200];  // [row=g*16+jj][k 0..191] +8 pad
  __shared__ __align__(16) u16 W2H[64 * 520];  // [row=g*16+jj][k 0..511] +8 pad
  __shared__ float gx[4][16][17];              // gate exchange, +1 pad

  const int tid = threadIdx.x;
  const int blk = blockIdx.x;
  const int q = blk & 3;    // batch quarter
  const int jt = blk >> 2;  // j-tile 0..31
  const int j0 = jt * 16;
  const int s = j0 >> 7;    // slice 0..3
  const int jbase = j0 & 127;

  // ---- one-time: split f32 weights, hi-planes -> LDS ----
  for (int i = tid; i < 64 * 192; i += NT) {
    const int r = i / 192, k = i % 192;
    const int col = (r >> 4) * 128 + jbase + (r & 15);
    const float w = (k < 64) ? Ws[(size_t)(s * 64 + k) * 512 + col]
                             : Us[(size_t)(s * 128 + (k - 64)) * 512 + col];
    W1H[r * 200 + k] = f2b(w);
  }
  for (int i = tid; i < 64 * 512; i += NT) {
    const int r = i >> 9, k = i & 511;
    const int col = (r >> 4) * 512 + j0 + (r & 15);
    W2H[r * 520 + k] = f2b(Wc[(size_t)k * 2048 + col]);
  }

  const int lane = tid & 63;
  const int g = tid >> 6;   // wave = gate
  const int lm = lane & 15;
  const int lq = lane >> 4;
  const int ko = lq * 8;

  // ---- one-time: lo-plane fragments -> VGPRs ----
  short8 w1l[6], w2l[16];
#pragma unroll
  for (int kt = 0; kt < 6; ++kt) {
    const int col = (g << 7) + jbase + lm;
#pragma unroll
    for (int e = 0; e < 8; ++e) {
      const int k = kt * 32 + ko + e;
      const float w = (k < 64) ? Ws[(size_t)(s * 64 + k) * 512 + col]
                               : Us[(size_t)(s * 128 + (k - 64)) * 512 + col];
      w1l[kt][e] = (short)f2b(w - b2f(f2b(w)));
    }
  }
#pragma unroll
  for (int kt = 0; kt < 16; ++kt) {
    const int col = (g << 9) + j0 + lm;
#pragma unroll
    for (int e = 0; e < 8; ++e) {
      const float w = Wc[(size_t)(kt * 32 + ko + e) * 2048 + col];
      w2l[kt][e] = (short)f2b(w - b2f(f2b(w)));
    }
  }
  const float biasv = biases[s * 512 + (g << 7) + jbase + lm];
  const float bcv = bcg[(g << 9) + j0 + lm];
  __syncthreads();

  const u16* w1r = &W1H[((g << 4) + lm) * 200];
  const u16* w2r = &W2H[((g << 4) + lm) * 520];
  const int brow = q * 16 + lm;
  const float* xrow = x + (size_t)brow * (512 * 256) + s * 64;
  const int hbase = brow * 512 + s * 128;
  const int arow_off = ((g << 6) + brow) * 512;

  // phase-3 mapping
  const int p3b = tid >> 4, p3j = tid & 15;
  const int p3ci = (q * 16 + p3b) * 512 + j0 + p3j;
  const size_t obase = (size_t)(q * 16 + p3b) * TSTEPS * 512 + j0 + p3j;
  float creg = 0.f, hprev = 0.f;

  // x prefetch registers for t=0
  float4 xa0, xb0, xa1, xb1;
  {
    const float* xp = xrow;
    xa0 = *(const float4*)(xp + ko);
    xb0 = *(const float4*)(xp + ko + 4);
    xa1 = *(const float4*)(xp + 32 + ko);
    xb1 = *(const float4*)(xp + 32 + ko + 4);
  }

  for (int t = 0; t < TSTEPS; ++t) {
    // ---- phase 1a: x-part of stage-1 (independent of h(t-1)) ----
    short8 xh[2], xl[2];
    split8v(xa0, xb0, xh[0], xl[0]);
    split8v(xa1, xb1, xh[1], xl[1]);
    floatx4 accA = {0.f, 0.f, 0.f, 0.f}, accB = {0.f, 0.f, 0.f, 0.f};
    floatx4 accC = {0.f, 0.f, 0.f, 0.f};
#pragma unroll
    for (int kt = 0; kt < 2; ++kt) {
      const short8 bh = ld8(w1r + kt * 32 + ko);
      accA = __builtin_amdgcn_mfma_f32_16x16x32_bf16(xh[kt], bh, accA, 0, 0, 0);
      accB = __builtin_amdgcn_mfma_f32_16x16x32_bf16(xl[kt], bh, accB, 0, 0, 0);
      accC = __builtin_amdgcn_mfma_f32_16x16x32_bf16(xh[kt], w1l[kt], accC, 0, 0, 0);
    }

    // ---- phase 0b: tagged h read (expect tag == t); one L3 RT typical ----
    short8 hh[4];
    {
      const u64 tg2 = ((u64)(unsigned)t << 32) | (unsigned)t;
      int tries = 0;
      for (;;) {
        u64 bad = 0;
#pragma unroll
        for (int kt = 0; kt < 4; ++kt) {
          const u64* p = (const u64*)&hbuf[hbase + kt * 32 + ko];
          const u64 d0 = ald64(p), d1 = ald64(p + 1);
          const u64 d2 = ald64(p + 2), d3 = ald64(p + 3);
          bad |= ((d0 ^ tg2) | (d1 ^ tg2) | (d2 ^ tg2) | (d3 ^ tg2)) & TAG_MASK;
          EXTRACT4(hh[kt], d0, d1, d2, d3);
        }
        if (__ballot(bad == 0) == ~0ULL) break;
        if (++tries > (1 << 12)) break;  // watchdog -> fast wrong answer
      }
    }

    // ---- phase 1b: h-part; activation; tagged act stores (no drain) ----
    {
#pragma unroll
      for (int kt = 0; kt < 4; ++kt) {
        const short8 bh = ld8(w1r + 64 + kt * 32 + ko);
        accA = __builtin_amdgcn_mfma_f32_16x16x32_bf16(hh[kt], bh, accA, 0, 0, 0);
        accC = __builtin_amdgcn_mfma_f32_16x16x32_bf16(hh[kt], w1l[2 + kt], accC, 0, 0, 0);
      }
      const int pp = (t & 1) * ACT_PLANE_U32;
#pragma unroll
      for (int r = 0; r < 4; ++r) {
        const int b = q * 16 + lq * 4 + r;
        const float pre = accA[r] + accB[r] + accC[r] + biasv;
        const float a = (g == 2) ? tanhf_fast(pre) : sigf(pre);
        ast32(&actbuf[pp + ((g << 6) + b) * 512 + j0 + lm],
              ((unsigned)f2b(a) << 16) | (unsigned)(t + 1));
      }
    }

    // ---- phase 2: tagged act read (expect tag == t+1); retries absorb skew ----
    short8 Ah[16];
    {
      const unsigned* ap = actbuf + (t & 1) * ACT_PLANE_U32 + arow_off;
      const u64 tg2 = ((u64)(unsigned)(t + 1) << 32) | (unsigned)(t + 1);
      int tries = 0;
      for (;;) {
        u64 bad = 0;
#pragma unroll
        for (int kt = 0; kt < 16; ++kt) {
          const u64* p = (const u64*)(ap + kt * 32 + ko);
          const u64 d0 = ald64(p), d1 = ald64(p + 1);
          const u64 d2 = ald64(p + 2), d3 = ald64(p + 3);
          bad |= ((d0 ^ tg2) | (d1 ^ tg2) | (d2 ^ tg2) | (d3 ^ tg2)) & TAG_MASK;
          EXTRACT4(Ah[kt], d0, d1, d2, d3);
        }
        if (__ballot(bad == 0) == ~0ULL) break;
        if (++tries > (1 << 12)) break;  // watchdog
      }
    }

    // ---- deferred out store + x(t+1) prefetch: acks hide under the GEMM ----
    if (t > 0) __builtin_nontemporal_store(hprev, &out[obase + (size_t)(t - 1) * 512]);
    {
      const float* xp = xrow + (size_t)(t < TSTEPS - 1 ? (t + 1) : t) * 256;
      xa0 = *(const float4*)(xp + ko);
      xb0 = *(const float4*)(xp + ko + 4);
      xa1 = *(const float4*)(xp + 32 + ko);
      xb1 = *(const float4*)(xp + 32 + ko + 4);
    }

    // ---- connector GEMM ----
    floatx4 a2a = {0.f, 0.f, 0.f, 0.f}, a2b = {0.f, 0.f, 0.f, 0.f};
    floatx4 a2c = {0.f, 0.f, 0.f, 0.f}, a2d = {0.f, 0.f, 0.f, 0.f};
#pragma unroll
    for (int kt = 0; kt < 16; kt += 2) {
      const int kb0 = kt * 32 + ko, kb1 = kb0 + 32;
      const short8 Bh0 = ld8(w2r + kb0), Bh1 = ld8(w2r + kb1);
      a2a = __builtin_amdgcn_mfma_f32_16x16x32_bf16(Ah[kt], Bh0, a2a, 0, 0, 0);
      a2b = __builtin_amdgcn_mfma_f32_16x16x32_bf16(Ah[kt], w2l[kt], a2b, 0, 0, 0);
      a2c = __builtin_amdgcn_mfma_f32_16x16x32_bf16(Ah[kt + 1], Bh1, a2c, 0, 0, 0);
      a2d = __builtin_amdgcn_mfma_f32_16x16x32_bf16(Ah[kt + 1], w2l[kt + 1], a2d, 0, 0, 0);
    }
#pragma unroll
    for (int r = 0; r < 4; ++r)
      gx[g][lq * 4 + r][lm] = (a2a[r] + a2c[r]) + (a2b[r] + a2d[r]) + bcv;
    __syncthreads();

    // ---- phase 3: elementwise update; tagged h store ----
    {
      const float it = sigf(gx[0][p3b][p3j]);
      const float ft = sigf(gx[1][p3b][p3j]);
      const float gt = tanhf_fast(gx[2][p3b][p3j]);
      const float ot = sigf(gx[3][p3b][p3j]);
      const float cn = ft * creg + it * gt;
      creg = cn;
      const float h = ot * tanhf_fast(cn);
      hprev = h;
      if (t < TSTEPS - 1) {
        ast32(&hbuf[p3ci], ((unsigned)f2b(h) << 16) | (unsigned)(t + 1));
      } else {
        __builtin_nontemporal_store(h, &out[obase + (size_t)t * 512]);
        __builtin_nontemporal_store(h, &out[16777216 + p3ci]);
        __builtin_nontemporal_store(cn, &out[16777216 + 32768 + p3ci]);
      }
    }
    __syncthreads();  // protect gx against next step's overwrite
  }
}

extern "C" void kernel_launch(void* const* d_in, const int* in_sizes, int n_in,
                              void* d_out, int out_size, void* d_ws, size_t ws_size,
                              hipStream_t stream) {
  const float* x = (const float*)d_in[0];
  const float* Ws = (const float*)d_in[1];
  const float* Us = (const float*)d_in[2];
  const float* biases = (const float*)d_in[3];
  const float* Wc = (const float*)d_in[4];
  const float* bc = (const float*)d_in[5];

  char* ws = (char*)d_ws;
  unsigned* hbuf = (unsigned*)(ws + WS_H);
  unsigned* actbuf = (unsigned*)(ws + WS_ACT);

  hipLaunchKernelGGL(init_ws_kernel, dim3(128), dim3(NT), 0, stream, (unsigned*)ws,
                     WS_ZERO_BYTES / 4);
  hipLaunchKernelGGL(slicelstm_kernel, dim3(NBLK), dim3(NT), 0, stream, x, Ws, Us,
                     biases, Wc, bc, (float*)d_out, actbuf, hbuf);
}

// Round 8
// 8267.753 us; speedup vs baseline: 1.1632x; 1.1632x over previous
//
#include <hip/hip_runtime.h>
#include <hip/hip_bf16.h>

// SliceLSTM persistent kernel for gfx950, round 12: dual-quarter interleave.
// Reverted to the verified round-10 exchange (flags + sc1/L3 relaxed atomics,
// single bf16 act/h planes; poll narrow, load wide once -- round-11's tag
// polling regressed 2.2x by making detection wide).
// 64 blocks x 256 thr: block = (j-tile, quarter-pair). Each block runs TWO
// independent batch-quarter roles (qA = blk&1, qB = qA+2) over the SAME
// j-tile, so weights (LDS hi-planes, VGPR lo-planes) are shared. The step
// schedule interleaves the roles so each role's drains/polls hide behind the
// other role's MFMA/compute:
//   A.stage1 -> B.x-MFMAs (no VMEM; overlaps A act-store drain) -> A.arrive1
//   -> A.out+xpf -> B.stage1-rest -> B.arrive1 -> B.out+xpf
//   -> A.{wait1, act loads, GEMM, phase3, arrive2}
//   -> B.{wait1, act loads, GEMM, phase3, arrive2}
// Barrier widths/participants unchanged vs round 10 (32-wide acts per
// quarter, 8-wide h slice-groups), watchdog-bounded polls.

typedef unsigned short u16;
typedef unsigned long long u64;
typedef __attribute__((ext_vector_type(8))) short short8;
typedef __attribute__((ext_vector_type(4))) float floatx4;

#define NT 256
#define NBLK 64
#define TSTEPS 512

// ---- workspace layout (bytes) ----
#define WS_FLAG1 0                        // 4 quarters x 32 u32 (256 B stride)
#define WS_FLAG2 1024                     // 16 groups x 16 u32
#define WS_H_HI 2048                      // 64 b x 512 j u16
#define WS_ZERO_BYTES (WS_H_HI + 65536)   // zeroed every call
#define WS_ACT_HI (WS_ZERO_BYTES)         // 2 planes x [4g][64b][512k] u16
#define ACT_PLANE 131072                  // elements per plane

__device__ __forceinline__ float b2f(u16 u) {
  unsigned v = ((unsigned)u) << 16;
  float f;
  __builtin_memcpy(&f, &v, 4);
  return f;
}
__device__ __forceinline__ u16 f2b(float f) {
  __hip_bfloat16 h = __float2bfloat16(f);  // RNE
  u16 u;
  __builtin_memcpy(&u, &h, 2);
  return u;
}
__device__ __forceinline__ float sigf(float x) { return 1.0f / (1.0f + __expf(-x)); }
__device__ __forceinline__ float tanhf_fast(float x) { return 2.0f * sigf(2.0f * x) - 1.0f; }
__device__ __forceinline__ short8 ld8(const u16* p) { return *(const short8*)p; }

// coherent 16B fragment load (sc1, straight from L3; relaxed -> batchable)
__device__ __forceinline__ short8 lda_frag(const u16* p) {
  union {
    u64 q[2];
    short8 s;
  } u;
  u.q[0] = __hip_atomic_load((const u64*)p, __ATOMIC_RELAXED, __HIP_MEMORY_SCOPE_AGENT);
  u.q[1] = __hip_atomic_load((const u64*)(p + 4), __ATOMIC_RELAXED, __HIP_MEMORY_SCOPE_AGENT);
  return u.s;
}
__device__ __forceinline__ void sta16(u16* p, u16 v) {
  __hip_atomic_store(p, v, __ATOMIC_RELAXED, __HIP_MEMORY_SCOPE_AGENT);
}

__device__ __forceinline__ void split8v(float4 a, float4 b, short8& hi, short8& lo) {
  float v[8] = {a.x, a.y, a.z, a.w, b.x, b.y, b.z, b.w};
#pragma unroll
  for (int i = 0; i < 8; ++i) {
    u16 h = f2b(v[i]);
    hi[i] = (short)h;
    lo[i] = (short)f2b(v[i] - b2f(h));
  }
}

// Wait-only half of a flag barrier: wave 0 polls, all threads gated after.
__device__ __forceinline__ void wait_flags(unsigned* flags, int nmask, unsigned target) {
  if (threadIdx.x < 64) {
    const int fi = threadIdx.x & nmask;
    int spins = 0;
    for (;;) {
      const unsigned v =
          __hip_atomic_load(&flags[fi], __ATOMIC_RELAXED, __HIP_MEMORY_SCOPE_AGENT);
      if (__ballot(v >= target) == ~0ULL) break;
      if (++spins > (1 << 24)) break;  // watchdog
      __builtin_amdgcn_s_sleep(1);
    }
  }
  __syncthreads();
}
// Arrive-only half: drain this block's stores, then publish the flag.
__device__ __forceinline__ void arrive_flags(unsigned* flags, int myidx, unsigned target) {
  asm volatile("s_waitcnt vmcnt(0)" ::: "memory");
  __syncthreads();
  if (threadIdx.x == 0)
    __hip_atomic_store(&flags[myidx], target, __ATOMIC_RELAXED, __HIP_MEMORY_SCOPE_AGENT);
}

__global__ void __launch_bounds__(NT) init_ws_kernel(unsigned* w, int n) {
  int i = blockIdx.x * blockDim.x + threadIdx.x;
  const int st = gridDim.x * blockDim.x;
  for (; i < n; i += st) w[i] = 0u;
}

__global__ void __launch_bounds__(NT, 1) slicelstm_kernel(
    const float* __restrict__ x, const float* __restrict__ Ws,
    const float* __restrict__ Us, const float* __restrict__ biases,
    const float* __restrict__ Wc, const float* __restrict__ bcg,
    float* __restrict__ out, u16* __restrict__ act_hi, u16* __restrict__ h_hi,
    unsigned* __restrict__ flagbase) {
  __shared__ __align__(16) u16 W1H[64 * 200];  // [row=g*16+jj][k 0..191] +8 pad
  __shared__ __align__(16) u16 W2H[64 * 520];  // [row=g*16+jj][k 0..511] +8 pad
  __shared__ float gx[2][4][16][17];           // per-role gate exchange, +1 pad

  const int tid = threadIdx.x;
  const int blk = blockIdx.x;
  const int qA = blk & 1;       // role-A quarter (0 or 1)
  const int qB = qA + 2;        // role-B quarter (2 or 3)
  const int jt = blk >> 1;      // j-tile 0..31 (shared by both roles)
  const int j0 = jt * 16;
  const int s = j0 >> 7;        // slice 0..3
  const int jbase = j0 & 127;
  unsigned* flags1A = flagbase + qA * 64;                  // 32 flags
  unsigned* flags1B = flagbase + qB * 64;
  unsigned* flags2A = flagbase + 256 + (qA * 4 + s) * 16;  // 8 flags
  unsigned* flags2B = flagbase + 256 + (qB * 4 + s) * 16;

  // ---- one-time: split f32 weights, hi-planes -> LDS (jt-only, shared) ----
  for (int i = tid; i < 64 * 192; i += NT) {
    const int r = i / 192, k = i % 192;
    const int col = (r >> 4) * 128 + jbase + (r & 15);
    const float w = (k < 64) ? Ws[(size_t)(s * 64 + k) * 512 + col]
                             : Us[(size_t)(s * 128 + (k - 64)) * 512 + col];
    W1H[r * 200 + k] = f2b(w);
  }
  for (int i = tid; i < 64 * 512; i += NT) {
    const int r = i >> 9, k = i & 511;
    const int col = (r >> 4) * 512 + j0 + (r & 15);
    W2H[r * 520 + k] = f2b(Wc[(size_t)k * 2048 + col]);
  }

  const int lane = tid & 63;
  const int g = tid >> 6;   // wave = gate
  const int lm = lane & 15;
  const int lq = lane >> 4;
  const int ko = lq * 8;

  // ---- one-time: lo-plane fragments -> VGPRs (shared across roles) ----
  short8 w1l[6], w2l[16];
#pragma unroll
  for (int kt = 0; kt < 6; ++kt) {
    const int col = (g << 7) + jbase + lm;
#pragma unroll
    for (int e = 0; e < 8; ++e) {
      const int k = kt * 32 + ko + e;
      const float w = (k < 64) ? Ws[(size_t)(s * 64 + k) * 512 + col]
                               : Us[(size_t)(s * 128 + (k - 64)) * 512 + col];
      w1l[kt][e] = (short)f2b(w - b2f(f2b(w)));
    }
  }
#pragma unroll
  for (int kt = 0; kt < 16; ++kt) {
    const int col = (g << 9) + j0 + lm;
#pragma unroll
    for (int e = 0; e < 8; ++e) {
      const float w = Wc[(size_t)(kt * 32 + ko + e) * 2048 + col];
      w2l[kt][e] = (short)f2b(w - b2f(f2b(w)));
    }
  }
  const float biasv = biases[s * 512 + (g << 7) + jbase + lm];
  const float bcv = bcg[(g << 9) + j0 + lm];
  __syncthreads();

  const u16* w1r = &W1H[((g << 4) + lm) * 200];
  const u16* w2r = &W2H[((g << 4) + lm) * 520];
  const int browA = qA * 16 + lm;
  const int browB = qB * 16 + lm;
  const float* xrowA = x + (size_t)browA * (512 * 256) + s * 64;
  const float* xrowB = x + (size_t)browB * (512 * 256) + s * 64;
  const int hbaseA = browA * 512 + s * 128;
  const int hbaseB = browB * 512 + s * 128;
  const int arowA = ((g << 6) + browA) * 512;
  const int arowB = ((g << 6) + browB) * 512;

  // phase-3 mapping
  const int p3b = tid >> 4, p3j = tid & 15;
  const int p3ciA = (qA * 16 + p3b) * 512 + j0 + p3j;
  const int p3ciB = (qB * 16 + p3b) * 512 + j0 + p3j;
  const size_t obaseA = (size_t)(qA * 16 + p3b) * TSTEPS * 512 + j0 + p3j;
  const size_t obaseB = (size_t)(qB * 16 + p3b) * TSTEPS * 512 + j0 + p3j;
  float cregA = 0.f, hprevA = 0.f, cregB = 0.f, hprevB = 0.f;

  // x prefetch registers for t=0 (both roles)
  float4 xa0A, xb0A, xa1A, xb1A, xa0B, xb0B, xa1B, xb1B;
  {
    const float* xp = xrowA;
    xa0A = *(const float4*)(xp + ko);
    xb0A = *(const float4*)(xp + ko + 4);
    xa1A = *(const float4*)(xp + 32 + ko);
    xb1A = *(const float4*)(xp + 32 + ko + 4);
    const float* xq = xrowB;
    xa0B = *(const float4*)(xq + ko);
    xb0B = *(const float4*)(xq + ko + 4);
    xa1B = *(const float4*)(xq + 32 + ko);
    xb1B = *(const float4*)(xq + 32 + ko + 4);
  }

  for (int t = 0; t < TSTEPS; ++t) {
    const int pp = (t & 1) * ACT_PLANE;
    // ======== role A: stage-1 ========
    floatx4 aA = {0.f, 0.f, 0.f, 0.f}, aB = {0.f, 0.f, 0.f, 0.f};
    floatx4 aC = {0.f, 0.f, 0.f, 0.f};
    {
      short8 xh[2], xl[2];
      split8v(xa0A, xb0A, xh[0], xl[0]);
      split8v(xa1A, xb1A, xh[1], xl[1]);
#pragma unroll
      for (int kt = 0; kt < 2; ++kt) {
        const short8 bh = ld8(w1r + kt * 32 + ko);
        aA = __builtin_amdgcn_mfma_f32_16x16x32_bf16(xh[kt], bh, aA, 0, 0, 0);
        aB = __builtin_amdgcn_mfma_f32_16x16x32_bf16(xl[kt], bh, aB, 0, 0, 0);
        aC = __builtin_amdgcn_mfma_f32_16x16x32_bf16(xh[kt], w1l[kt], aC, 0, 0, 0);
      }
      wait_flags(flags2A, 7, (unsigned)t);
      short8 hh[4];
#pragma unroll
      for (int kt = 0; kt < 4; ++kt) hh[kt] = lda_frag(&h_hi[hbaseA + kt * 32 + ko]);
      asm volatile("s_waitcnt vmcnt(0)" ::: "memory");
      __builtin_amdgcn_sched_barrier(0);
#pragma unroll
      for (int kt = 0; kt < 4; ++kt) {
        const short8 bh = ld8(w1r + 64 + kt * 32 + ko);
        aA = __builtin_amdgcn_mfma_f32_16x16x32_bf16(hh[kt], bh, aA, 0, 0, 0);
        aC = __builtin_amdgcn_mfma_f32_16x16x32_bf16(hh[kt], w1l[2 + kt], aC, 0, 0, 0);
      }
#pragma unroll
      for (int r = 0; r < 4; ++r) {
        const int b = qA * 16 + lq * 4 + r;
        const float pre = aA[r] + aB[r] + aC[r] + biasv;
        const float a = (g == 2) ? tanhf_fast(pre) : sigf(pre);
        sta16(&act_hi[pp + ((g << 6) + b) * 512 + j0 + lm], f2b(a));
      }
    }
    // ======== role B: x-part (no VMEM -> overlaps A's act-store drain) ====
    floatx4 bA = {0.f, 0.f, 0.f, 0.f}, bB = {0.f, 0.f, 0.f, 0.f};
    floatx4 bC = {0.f, 0.f, 0.f, 0.f};
    short8 xhB[2], xlB[2];
    split8v(xa0B, xb0B, xhB[0], xlB[0]);
    split8v(xa1B, xb1B, xhB[1], xlB[1]);
#pragma unroll
    for (int kt = 0; kt < 2; ++kt) {
      const short8 bh = ld8(w1r + kt * 32 + ko);
      bA = __builtin_amdgcn_mfma_f32_16x16x32_bf16(xhB[kt], bh, bA, 0, 0, 0);
      bB = __builtin_amdgcn_mfma_f32_16x16x32_bf16(xlB[kt], bh, bB, 0, 0, 0);
      bC = __builtin_amdgcn_mfma_f32_16x16x32_bf16(xhB[kt], w1l[kt], bC, 0, 0, 0);
    }
    // ---- A arrive1; A deferred out-store + x(t+1) prefetch in the gap ----
    arrive_flags(flags1A, jt, (unsigned)(t + 1));
    if (t > 0) __builtin_nontemporal_store(hprevA, &out[obaseA + (size_t)(t - 1) * 512]);
    {
      const float* xp = xrowA + (size_t)(t < TSTEPS - 1 ? (t + 1) : t) * 256;
      xa0A = *(const float4*)(xp + ko);
      xb0A = *(const float4*)(xp + ko + 4);
      xa1A = *(const float4*)(xp + 32 + ko);
      xb1A = *(const float4*)(xp + 32 + ko + 4);
    }
    // ======== role B: finish stage-1 ========
    {
      wait_flags(flags2B, 7, (unsigned)t);
      short8 hh[4];
#pragma unroll
      for (int kt = 0; kt < 4; ++kt) hh[kt] = lda_frag(&h_hi[hbaseB + kt * 32 + ko]);
      asm volatile("s_waitcnt vmcnt(0)" ::: "memory");
      __builtin_amdgcn_sched_barrier(0);
#pragma unroll
      for (int kt = 0; kt < 4; ++kt) {
        const short8 bh = ld8(w1r + 64 + kt * 32 + ko);
        bA = __builtin_amdgcn_mfma_f32_16x16x32_bf16(hh[kt], bh, bA, 0, 0, 0);
        bC = __builtin_amdgcn_mfma_f32_16x16x32_bf16(hh[kt], w1l[2 + kt], bC, 0, 0, 0);
      }
#pragma unroll
      for (int r = 0; r < 4; ++r) {
        const int b = qB * 16 + lq * 4 + r;
        const float pre = bA[r] + bB[r] + bC[r] + biasv;
        const float a = (g == 2) ? tanhf_fast(pre) : sigf(pre);
        sta16(&act_hi[pp + ((g << 6) + b) * 512 + j0 + lm], f2b(a));
      }
    }
    arrive_flags(flags1B, jt, (unsigned)(t + 1));
    if (t > 0) __builtin_nontemporal_store(hprevB, &out[obaseB + (size_t)(t - 1) * 512]);
    {
      const float* xp = xrowB + (size_t)(t < TSTEPS - 1 ? (t + 1) : t) * 256;
      xa0B = *(const float4*)(xp + ko);
      xb0B = *(const float4*)(xp + ko + 4);
      xa1B = *(const float4*)(xp + 32 + ko);
      xb1B = *(const float4*)(xp + 32 + ko + 4);
    }

    // ======== role A: connector + update ========
    {
      wait_flags(flags1A, 31, (unsigned)(t + 1));
      short8 Ah[16];
      const u16* ahp = act_hi + pp + arowA;
#pragma unroll
      for (int kt = 0; kt < 16; ++kt) Ah[kt] = lda_frag(ahp + kt * 32 + ko);
      asm volatile("s_waitcnt vmcnt(0)" ::: "memory");
      __builtin_amdgcn_sched_barrier(0);
      floatx4 c0 = {0.f, 0.f, 0.f, 0.f}, c1 = {0.f, 0.f, 0.f, 0.f};
      floatx4 c2 = {0.f, 0.f, 0.f, 0.f}, c3 = {0.f, 0.f, 0.f, 0.f};
#pragma unroll
      for (int kt = 0; kt < 16; kt += 2) {
        const int kb0 = kt * 32 + ko, kb1 = kb0 + 32;
        const short8 Bh0 = ld8(w2r + kb0), Bh1 = ld8(w2r + kb1);
        c0 = __builtin_amdgcn_mfma_f32_16x16x32_bf16(Ah[kt], Bh0, c0, 0, 0, 0);
        c1 = __builtin_amdgcn_mfma_f32_16x16x32_bf16(Ah[kt], w2l[kt], c1, 0, 0, 0);
        c2 = __builtin_amdgcn_mfma_f32_16x16x32_bf16(Ah[kt + 1], Bh1, c2, 0, 0, 0);
        c3 = __builtin_amdgcn_mfma_f32_16x16x32_bf16(Ah[kt + 1], w2l[kt + 1], c3, 0, 0, 0);
      }
#pragma unroll
      for (int r = 0; r < 4; ++r)
        gx[0][g][lq * 4 + r][lm] = (c0[r] + c2[r]) + (c1[r] + c3[r]) + bcv;
    }
    __syncthreads();
    {
      const float it = sigf(gx[0][0][p3b][p3j]);
      const float ft = sigf(gx[0][1][p3b][p3j]);
      const float gt = tanhf_fast(gx[0][2][p3b][p3j]);
      const float ot = sigf(gx[0][3][p3b][p3j]);
      const float cn = ft * cregA + it * gt;
      cregA = cn;
      const float h = ot * tanhf_fast(cn);
      hprevA = h;
      if (t < TSTEPS - 1) {
        sta16(&h_hi[p3ciA], f2b(h));
      } else {
        __builtin_nontemporal_store(h, &out[obaseA + (size_t)t * 512]);
        __builtin_nontemporal_store(h, &out[16777216 + p3ciA]);
        __builtin_nontemporal_store(cregA, &out[16777216 + 32768 + p3ciA]);
      }
    }
    if (t < TSTEPS - 1) arrive_flags(flags2A, jt & 7, (unsigned)(t + 1));

    // ======== role B: connector + update ========
    {
      wait_flags(flags1B, 31, (unsigned)(t + 1));
      short8 Ah[16];
      const u16* ahp = act_hi + pp + arowB;
#pragma unroll
      for (int kt = 0; kt < 16; ++kt) Ah[kt] = lda_frag(ahp + kt * 32 + ko);
      asm volatile("s_waitcnt vmcnt(0)" ::: "memory");
      __builtin_amdgcn_sched_barrier(0);
      floatx4 c0 = {0.f, 0.f, 0.f, 0.f}, c1 = {0.f, 0.f, 0.f, 0.f};
      floatx4 c2 = {0.f, 0.f, 0.f, 0.f}, c3 = {0.f, 0.f, 0.f, 0.f};
#pragma unroll
      for (int kt = 0; kt < 16; kt += 2) {
        const int kb0 = kt * 32 + ko, kb1 = kb0 + 32;
        const short8 Bh0 = ld8(w2r + kb0), Bh1 = ld8(w2r + kb1);
        c0 = __builtin_amdgcn_mfma_f32_16x16x32_bf16(Ah[kt], Bh0, c0, 0, 0, 0);
        c1 = __builtin_amdgcn_mfma_f32_16x16x32_bf16(Ah[kt], w2l[kt], c1, 0, 0, 0);
        c2 = __builtin_amdgcn_mfma_f32_16x16x32_bf16(Ah[kt + 1], Bh1, c2, 0, 0, 0);
        c3 = __builtin_amdgcn_mfma_f32_16x16x32_bf16(Ah[kt + 1], w2l[kt + 1], c3, 0, 0, 0);
      }
#pragma unroll
      for (int r = 0; r < 4; ++r)
        gx[1][g][lq * 4 + r][lm] = (c0[r] + c2[r]) + (c1[r] + c3[r]) + bcv;
    }
    __syncthreads();
    {
      const float it = sigf(gx[1][0][p3b][p3j]);
      const float ft = sigf(gx[1][1][p3b][p3j]);
      const float gt = tanhf_fast(gx[1][2][p3b][p3j]);
      const float ot = sigf(gx[1][3][p3b][p3j]);
      const float cn = ft * cregB + it * gt;
      cregB = cn;
      const float h = ot * tanhf_fast(cn);
      hprevB = h;
      if (t < TSTEPS - 1) {
        sta16(&h_hi[p3ciB], f2b(h));
      } else {
        __builtin_nontemporal_store(h, &out[obaseB + (size_t)t * 512]);
        __builtin_nontemporal_store(h, &out[16777216 + p3ciB]);
        __builtin_nontemporal_store(cregB, &out[16777216 + 32768 + p3ciB]);
      }
    }
    if (t < TSTEPS - 1) arrive_flags(flags2B, jt & 7, (unsigned)(t + 1));
  }
}

extern "C" void kernel_launch(void* const* d_in, const int* in_sizes, int n_in,
                              void* d_out, int out_size, void* d_ws, size_t ws_size,
                              hipStream_t stream) {
  const float* x = (const float*)d_in[0];
  const float* Ws = (const float*)d_in[1];
  const float* Us = (const float*)d_in[2];
  const float* biases = (const float*)d_in[3];
  const float* Wc = (const float*)d_in[4];
  const float* bc = (const float*)d_in[5];

  char* ws = (char*)d_ws;
  unsigned* flagbase = (unsigned*)(ws + WS_FLAG1);
  u16* h_hi = (u16*)(ws + WS_H_HI);
  u16* act_hi = (u16*)(ws + WS_ACT_HI);

  hipLaunchKernelGGL(init_ws_kernel, dim3(64), dim3(NT), 0, stream, (unsigned*)ws,
                     WS_ZERO_BYTES / 4);
  hipLaunchKernelGGL(slicelstm_kernel, dim3(NBLK), dim3(NT), 0, stream, x, Ws, Us,
                     biases, Wc, bc, (float*)d_out, act_hi, h_hi, flagbase);
}

// Round 10
// 5669.209 us; speedup vs baseline: 1.6964x; 1.4584x over previous
//
#include <hip/hip_runtime.h>
#include <hip/hip_bf16.h>

// SliceLSTM persistent kernel for gfx950, round 13 (resubmit; round-9 bench
// died at container acquisition -- no kernel signal).
// Base = verified round-10 (4442us): 128 blocks x 256 thr (4 quarters x 32
// j-tiles, wave = gate), acts exchanged via single bf16 plane + 32-wide flag
// barrier1 (arrive/wait split, out-store + x-prefetch in the gap).
// Round-13 delta: the h exchange (8-wide slice group) drops its flag barrier
// entirely and becomes tag-in-data: h word = u32 (bf16(h)<<16 | step+1),
// stored with NO drain; readers issue the tagged loads SPECULATIVELY before
// the x-part MFMAs (overlap before the poll -- r12 lesson: waves are
// in-order, so overlap work must precede the wait), then validate tags and
// retry only on mismatch. Deletes arrive2 (drain+flag RT) and wait2 (detect
// RT) from the per-step chain. Safety: barrier1(t+1) completes only after
// every group-mate consumed h(t), and tag t+1 is written only after
// wait1(t+1) -- the single-buffer overwrite hazard is excluded (mechanism
// correctness-verified in round 11). Acts stay flag-based: round 11 measured
// that tag-polling WIDE data at 32-block skew retry-storms (poll narrow,
// load wide once).

typedef unsigned short u16;
typedef unsigned long long u64;
typedef __attribute__((ext_vector_type(8))) short short8;
typedef __attribute__((ext_vector_type(4))) float floatx4;

#define NT 256
#define NBLK 128
#define TSTEPS 512

// ---- workspace layout (bytes) ----
#define WS_FLAG1 0                        // 4 quarters x 32 u32 (256 B stride)
#define WS_H 1024                         // 64 b x 512 j u32 (tagged h)
#define WS_ZERO_BYTES (WS_H + 131072)     // zeroed every call
#define WS_ACT_HI (WS_ZERO_BYTES)         // 2 planes x [4g][64b][512k] u16
#define ACT_PLANE 131072                  // u16 elements per plane

__device__ __forceinline__ float b2f(u16 u) {
  unsigned v = ((unsigned)u) << 16;
  float f;
  __builtin_memcpy(&f, &v, 4);
  return f;
}
__device__ __forceinline__ u16 f2b(float f) {
  __hip_bfloat16 h = __float2bfloat16(f);  // RNE
  u16 u;
  __builtin_memcpy(&u, &h, 2);
  return u;
}
__device__ __forceinline__ float sigf(float x) { return 1.0f / (1.0f + __expf(-x)); }
__device__ __forceinline__ float tanhf_fast(float x) { return 2.0f * sigf(2.0f * x) - 1.0f; }
__device__ __forceinline__ short8 ld8(const u16* p) { return *(const short8*)p; }

// coherent 16B fragment load (sc1, straight from L3; relaxed -> batchable)
__device__ __forceinline__ short8 lda_frag(const u16* p) {
  union {
    u64 q[2];
    short8 s;
  } u;
  u.q[0] = __hip_atomic_load((const u64*)p, __ATOMIC_RELAXED, __HIP_MEMORY_SCOPE_AGENT);
  u.q[1] = __hip_atomic_load((const u64*)(p + 4), __ATOMIC_RELAXED, __HIP_MEMORY_SCOPE_AGENT);
  return u.s;
}
__device__ __forceinline__ void sta16(u16* p, u16 v) {
  __hip_atomic_store(p, v, __ATOMIC_RELAXED, __HIP_MEMORY_SCOPE_AGENT);
}
__device__ __forceinline__ u64 ald64(const u64* p) {
  return __hip_atomic_load(p, __ATOMIC_RELAXED, __HIP_MEMORY_SCOPE_AGENT);
}
__device__ __forceinline__ void ast32(unsigned* p, unsigned v) {
  __hip_atomic_store(p, v, __ATOMIC_RELAXED, __HIP_MEMORY_SCOPE_AGENT);
}

__device__ __forceinline__ void split8v(float4 a, float4 b, short8& hi, short8& lo) {
  float v[8] = {a.x, a.y, a.z, a.w, b.x, b.y, b.z, b.w};
#pragma unroll
  for (int i = 0; i < 8; ++i) {
    u16 h = f2b(v[i]);
    hi[i] = (short)h;
    lo[i] = (short)f2b(v[i] - b2f(h));
  }
}

#define TAG_MASK 0x0000ffff0000ffffULL
// extract the two bf16 hi-halves of four tagged u64s into a short8
#define EXTRACT4(dst, d0, d1, d2, d3) \
  do {                                \
    dst[0] = (short)((d0) >> 16);     \
    dst[1] = (short)((d0) >> 48);     \
    dst[2] = (short)((d1) >> 16);     \
    dst[3] = (short)((d1) >> 48);     \
    dst[4] = (short)((d2) >> 16);     \
    dst[5] = (short)((d2) >> 48);     \
    dst[6] = (short)((d3) >> 16);     \
    dst[7] = (short)((d3) >> 48);     \
  } while (0)

// Wait-only half of the acts flag barrier: wave 0 polls, all gated after.
__device__ __forceinline__ void wait_flags(unsigned* flags, int nmask, unsigned target) {
  if (threadIdx.x < 64) {
    const int fi = threadIdx.x & nmask;
    int spins = 0;
    for (;;) {
      const unsigned v =
          __hip_atomic_load(&flags[fi], __ATOMIC_RELAXED, __HIP_MEMORY_SCOPE_AGENT);
      if (__ballot(v >= target) == ~0ULL) break;
      if (++spins > (1 << 24)) break;  // watchdog
      __builtin_amdgcn_s_sleep(1);
    }
  }
  __syncthreads();
}
// Arrive-only half: drain this block's stores, then publish the flag.
__device__ __forceinline__ void arrive_flags(unsigned* flags, int myidx, unsigned target) {
  asm volatile("s_waitcnt vmcnt(0)" ::: "memory");
  __syncthreads();
  if (threadIdx.x == 0)
    __hip_atomic_store(&flags[myidx], target, __ATOMIC_RELAXED, __HIP_MEMORY_SCOPE_AGENT);
}

__global__ void __launch_bounds__(NT) init_ws_kernel(unsigned* w, int n) {
  int i = blockIdx.x * blockDim.x + threadIdx.x;
  const int st = gridDim.x * blockDim.x;
  for (; i < n; i += st) w[i] = 0u;
}

__global__ void __launch_bounds__(NT, 1) slicelstm_kernel(
    const float* __restrict__ x, const float* __restrict__ Ws,
    const float* __restrict__ Us, const float* __restrict__ biases,
    const float* __restrict__ Wc, const float* __restrict__ bcg,
    float* __restrict__ out, u16* __restrict__ act_hi, unsigned* __restrict__ hbuf,
    unsigned* __restrict__ flagbase) {
  __shared__ __align__(16) u16 W1H[64 * 200];  // [row=g*16+jj][k 0..191] +8 pad
  __shared__ __align__(16) u16 W2H[64 * 520];  // [row=g*16+jj][k 0..511] +8 pad
  __shared__ float gx[4][16][17];              // gate exchange, +1 pad

  const int tid = threadIdx.x;
  const int blk = blockIdx.x;
  const int q = blk & 3;    // batch quarter
  const int jt = blk >> 2;  // j-tile 0..31
  const int j0 = jt * 16;
  const int s = j0 >> 7;    // slice 0..3
  const int jbase = j0 & 127;
  unsigned* flags1 = flagbase + q * 64;  // 32 flags

  // ---- one-time: split f32 weights, hi-planes -> LDS ----
  for (int i = tid; i < 64 * 192; i += NT) {
    const int r = i / 192, k = i % 192;
    const int col = (r >> 4) * 128 + jbase + (r & 15);
    const float w = (k < 64) ? Ws[(size_t)(s * 64 + k) * 512 + col]
                             : Us[(size_t)(s * 128 + (k - 64)) * 512 + col];
    W1H[r * 200 + k] = f2b(w);
  }
  for (int i = tid; i < 64 * 512; i += NT) {
    const int r = i >> 9, k = i & 511;
    const int col = (r >> 4) * 512 + j0 + (r & 15);
    W2H[r * 520 + k] = f2b(Wc[(size_t)k * 2048 + col]);
  }

  const int lane = tid & 63;
  const int g = tid >> 6;   // wave = gate
  const int lm = lane & 15;
  const int lq = lane >> 4;
  const int ko = lq * 8;

  // ---- one-time: lo-plane fragments -> VGPRs ----
  short8 w1l[6], w2l[16];
#pragma unroll
  for (int kt = 0; kt < 6; ++kt) {
    const int col = (g << 7) + jbase + lm;
#pragma unroll
    for (int e = 0; e < 8; ++e) {
      const int k = kt * 32 + ko + e;
      const float w = (k < 64) ? Ws[(size_t)(s * 64 + k) * 512 + col]
                               : Us[(size_t)(s * 128 + (k - 64)) * 512 + col];
      w1l[kt][e] = (short)f2b(w - b2f(f2b(w)));
    }
  }
#pragma unroll
  for (int kt = 0; kt < 16; ++kt) {
    const int col = (g << 9) + j0 + lm;
#pragma unroll
    for (int e = 0; e < 8; ++e) {
      const float w = Wc[(size_t)(kt * 32 + ko + e) * 2048 + col];
      w2l[kt][e] = (short)f2b(w - b2f(f2b(w)));
    }
  }
  const float biasv = biases[s * 512 + (g << 7) + jbase + lm];
  const float bcv = bcg[(g << 9) + j0 + lm];
  __syncthreads();

  const u16* w1r = &W1H[((g << 4) + lm) * 200];
  const u16* w2r = &W2H[((g << 4) + lm) * 520];
  const int brow = q * 16 + lm;
  const float* xrow = x + (size_t)brow * (512 * 256) + s * 64;
  const int hbase = brow * 512 + s * 128;  // u32 index into hbuf
  const int arow_off = ((g << 6) + brow) * 512;

  // phase-3 mapping
  const int p3b = tid >> 4, p3j = tid & 15;
  const int p3ci = (q * 16 + p3b) * 512 + j0 + p3j;
  const size_t obase = (size_t)(q * 16 + p3b) * TSTEPS * 512 + j0 + p3j;
  float creg = 0.f, hprev = 0.f;

  // x prefetch registers for t=0
  float4 xa0, xb0, xa1, xb1;
  {
    const float* xp = xrow;
    xa0 = *(const float4*)(xp + ko);
    xb0 = *(const float4*)(xp + ko + 4);
    xa1 = *(const float4*)(xp + 32 + ko);
    xb1 = *(const float4*)(xp + 32 + ko + 4);
  }

  for (int t = 0; t < TSTEPS; ++t) {
    // ---- speculative tagged h load: issue BEFORE the x-part so the L3 RT
    //      hides under the MFMAs (expect tag == t; zero-init covers t=0) ----
    u64 hd[4][4];
#pragma unroll
    for (int kt = 0; kt < 4; ++kt) {
      const u64* p = (const u64*)&hbuf[hbase + kt * 32 + ko];
#pragma unroll
      for (int i = 0; i < 4; ++i) hd[kt][i] = ald64(p + i);
    }

    // ---- phase 1a: x-part of stage-1 (independent of h(t-1)) ----
    short8 xh[2], xl[2];
    split8v(xa0, xb0, xh[0], xl[0]);
    split8v(xa1, xb1, xh[1], xl[1]);
    floatx4 accA = {0.f, 0.f, 0.f, 0.f}, accB = {0.f, 0.f, 0.f, 0.f};
    floatx4 accC = {0.f, 0.f, 0.f, 0.f};
#pragma unroll
    for (int kt = 0; kt < 2; ++kt) {
      const short8 bh = ld8(w1r + kt * 32 + ko);
      accA = __builtin_amdgcn_mfma_f32_16x16x32_bf16(xh[kt], bh, accA, 0, 0, 0);
      accB = __builtin_amdgcn_mfma_f32_16x16x32_bf16(xl[kt], bh, accB, 0, 0, 0);
      accC = __builtin_amdgcn_mfma_f32_16x16x32_bf16(xh[kt], w1l[kt], accC, 0, 0, 0);
    }

    // ---- resolve tagged h: validate tags, retry only on mismatch ----
    short8 hh[4];
    {
      const u64 tg2 = ((u64)(unsigned)t << 32) | (unsigned)t;
      int tries = 0;
      for (;;) {
        u64 bad = 0;
#pragma unroll
        for (int kt = 0; kt < 4; ++kt) {
          bad |= ((hd[kt][0] ^ tg2) | (hd[kt][1] ^ tg2) | (hd[kt][2] ^ tg2) |
                  (hd[kt][3] ^ tg2)) &
                 TAG_MASK;
          EXTRACT4(hh[kt], hd[kt][0], hd[kt][1], hd[kt][2], hd[kt][3]);
        }
        if (__ballot(bad == 0) == ~0ULL) break;
        if (++tries > (1 << 12)) break;  // watchdog -> fast wrong answer
#pragma unroll
        for (int kt = 0; kt < 4; ++kt) {
          const u64* p = (const u64*)&hbuf[hbase + kt * 32 + ko];
#pragma unroll
          for (int i = 0; i < 4; ++i) hd[kt][i] = ald64(p + i);
        }
      }
    }

    // ---- phase 1b: h-part; activation; act stores (hi plane only) ----
    {
#pragma unroll
      for (int kt = 0; kt < 4; ++kt) {
        const short8 bh = ld8(w1r + 64 + kt * 32 + ko);
        accA = __builtin_amdgcn_mfma_f32_16x16x32_bf16(hh[kt], bh, accA, 0, 0, 0);
        accC = __builtin_amdgcn_mfma_f32_16x16x32_bf16(hh[kt], w1l[2 + kt], accC, 0, 0, 0);
      }
      const int pp = (t & 1) * ACT_PLANE;
#pragma unroll
      for (int r = 0; r < 4; ++r) {
        const int b = q * 16 + lq * 4 + r;
        const float pre = accA[r] + accB[r] + accC[r] + biasv;
        const float a = (g == 2) ? tanhf_fast(pre) : sigf(pre);
        sta16(&act_hi[pp + ((g << 6) + b) * 512 + j0 + lm], f2b(a));
      }
    }
    // ---- arrive1; fill the skew gap with out store + x(t+1) prefetch ----
    arrive_flags(flags1, jt, (unsigned)(t + 1));
    if (t > 0) __builtin_nontemporal_store(hprev, &out[obase + (size_t)(t - 1) * 512]);
    {
      const float* xp = xrow + (size_t)(t < TSTEPS - 1 ? (t + 1) : t) * 256;
      xa0 = *(const float4*)(xp + ko);
      xb0 = *(const float4*)(xp + ko + 4);
      xa1 = *(const float4*)(xp + 32 + ko);
      xb1 = *(const float4*)(xp + 32 + ko + 4);
    }
    __builtin_amdgcn_sched_barrier(0);  // pin issue before the wait loop
    wait_flags(flags1, 31, (unsigned)(t + 1));

    // ---- phase 2: act loads (one drain); connector GEMM ----
    short8 Ah[16];
    {
      const u16* ahp = act_hi + (t & 1) * ACT_PLANE + arow_off;
#pragma unroll
      for (int kt = 0; kt < 16; ++kt) Ah[kt] = lda_frag(ahp + kt * 32 + ko);
    }
    asm volatile("s_waitcnt vmcnt(0)" ::: "memory");
    __builtin_amdgcn_sched_barrier(0);
    floatx4 a2a = {0.f, 0.f, 0.f, 0.f}, a2b = {0.f, 0.f, 0.f, 0.f};
    floatx4 a2c = {0.f, 0.f, 0.f, 0.f}, a2d = {0.f, 0.f, 0.f, 0.f};
#pragma unroll
    for (int kt = 0; kt < 16; kt += 2) {
      const int kb0 = kt * 32 + ko, kb1 = kb0 + 32;
      const short8 Bh0 = ld8(w2r + kb0), Bh1 = ld8(w2r + kb1);
      a2a = __builtin_amdgcn_mfma_f32_16x16x32_bf16(Ah[kt], Bh0, a2a, 0, 0, 0);
      a2b = __builtin_amdgcn_mfma_f32_16x16x32_bf16(Ah[kt], w2l[kt], a2b, 0, 0, 0);
      a2c = __builtin_amdgcn_mfma_f32_16x16x32_bf16(Ah[kt + 1], Bh1, a2c, 0, 0, 0);
      a2d = __builtin_amdgcn_mfma_f32_16x16x32_bf16(Ah[kt + 1], w2l[kt + 1], a2d, 0, 0, 0);
    }
#pragma unroll
    for (int r = 0; r < 4; ++r)
      gx[g][lq * 4 + r][lm] = (a2a[r] + a2c[r]) + (a2b[r] + a2d[r]) + bcv;
    __syncthreads();

    // ---- phase 3: elementwise update; tagged h store (NO drain, NO flag) ----
    {
      const float it = sigf(gx[0][p3b][p3j]);
      const float ft = sigf(gx[1][p3b][p3j]);
      const float gt = tanhf_fast(gx[2][p3b][p3j]);
      const float ot = sigf(gx[3][p3b][p3j]);
      const float cn = ft * creg + it * gt;
      creg = cn;
      const float h = ot * tanhf_fast(cn);
      hprev = h;
      if (t < TSTEPS - 1) {
        ast32(&hbuf[p3ci], ((unsigned)f2b(h) << 16) | (unsigned)(t + 1));
      } else {
        __builtin_nontemporal_store(h, &out[obase + (size_t)t * 512]);
        __builtin_nontemporal_store(h, &out[16777216 + p3ci]);
        __builtin_nontemporal_store(cn, &out[16777216 + 32768 + p3ci]);
      }
    }
  }
}

extern "C" void kernel_launch(void* const* d_in, const int* in_sizes, int n_in,
                              void* d_out, int out_size, void* d_ws, size_t ws_size,
                              hipStream_t stream) {
  const float* x = (const float*)d_in[0];
  const float* Ws = (const float*)d_in[1];
  const float* Us = (const float*)d_in[2];
  const float* biases = (const float*)d_in[3];
  const float* Wc = (const float*)d_in[4];
  const float* bc = (const float*)d_in[5];

  char* ws = (char*)d_ws;
  unsigned* flagbase = (unsigned*)(ws + WS_FLAG1);
  unsigned* hbuf = (unsigned*)(ws + WS_H);
  u16* act_hi = (u16*)(ws + WS_ACT_HI);

  hipLaunchKernelGGL(init_ws_kernel, dim3(64), dim3(NT), 0, stream, (unsigned*)ws,
                     WS_ZERO_BYTES / 4);
  hipLaunchKernelGGL(slicelstm_kernel, dim3(NBLK), dim3(NT), 0, stream, x, Ws, Us,
                     biases, Wc, bc, (float*)d_out, act_hi, hbuf, flagbase);
}